// Round 7
// baseline (458.821 us; speedup 1.0000x reference)
//
#include <hip/hip_runtime.h>
#include <float.h>
#include <math.h>

#define BATCH 8
#define NPTS 4096
#define KNN 10
#define BN (BATCH * NPTS)          // 32768 points per cloud
#define NCLOUD (2 * BATCH)         // 16 clouds
#define NLIST 4                    // sorted sub-lists per cloud
#define LISTN (NPTS / NLIST)       // 1024 elements per list
#define PAD 32                     // sentinel guard band each side (covers prefetch)
#define LSTRIDE (LISTN + 2 * PAD)
#define MAXCH 20                   // cap: 8-candidate chunks per list-direction

__device__ float4 g_spts[NCLOUD][NLIST][LSTRIDE]; // sorted (x,y,z,|p|^2)+guards
__device__ unsigned short g_perm[NCLOUD][NPTS];   // [list*1024+pos] -> orig idx
__device__ float4 g_nrm[2 * BN];                  // normals, original order
__device__ unsigned g_defer[NCLOUD * NPTS];       // (cloud<<12)|orig
__device__ unsigned g_defer_cnt;

__device__ inline float med3f(float x, float a, float b) {
    return __builtin_amdgcn_fmed3f(x, a, b);
}

// branchless sorted insert of key into ascending k[0..9] (drop largest)
#define INSERT(karr, key)                                              \
    do {                                                               \
        _Pragma("unroll")                                              \
        for (int _j = KNN - 1; _j >= 1; --_j)                          \
            karr[_j] = med3f((key), karr[_j - 1], karr[_j]);           \
        karr[0] = fminf((key), karr[0]);                               \
    } while (0)

// distance + pack(list*1024+pos, 12b) + insert; guards have w=1e30 ->
// d ~1e30 (finite), never beats the 1e28 init -> junk idx never selected
#define PROC1(_p, _pos12)                                              \
    do {                                                               \
        float _d = fmaf((_p).z, a0z, fmaf((_p).y, a0y, fmaf((_p).x, a0x, (_p).w))); \
        float _k = __uint_as_float((__float_as_uint(_d) & 0xFFFFF000u) | ((unsigned)(_pos12) & 0xFFFu)); \
        INSERT(kq, _k);                                                \
    } while (0)

#define PROC8(P, _b)                                                   \
    do {                                                               \
        PROC1(P##0, (_b) + 0); PROC1(P##1, (_b) + 1);                  \
        PROC1(P##2, (_b) + 2); PROC1(P##3, (_b) + 3);                  \
        PROC1(P##4, (_b) + 4); PROC1(P##5, (_b) + 5);                  \
        PROC1(P##6, (_b) + 6); PROC1(P##7, (_b) + 7);                  \
    } while (0)

#define LOADG(P, _cp, _i)                                              \
    do {                                                               \
        P##0 = (_cp)[(_i) + 0]; P##1 = (_cp)[(_i) + 1];                \
        P##2 = (_cp)[(_i) + 2]; P##3 = (_cp)[(_i) + 3];                \
        P##4 = (_cp)[(_i) + 4]; P##5 = (_cp)[(_i) + 5];                \
        P##6 = (_cp)[(_i) + 6]; P##7 = (_cp)[(_i) + 7];                \
    } while (0)

// prune threshold ~ d10^2 (+ margin for 12-bit key truncation); keys init
// 1e28 -> thr < guard dxe^2 = 1e30 -> walk always terminates at sentinels
#define RETHR() (kq[KNN - 1] + qw2 + fmaf(fabsf(kq[KNN - 1]), 2e-3f, 1e-4f))

// capped window walk over one list, one direction; A/B register double-buffer.
// Break is exact: edge-of-chunk dx^2 >= thr => all unseen in this direction
// are farther. Cap => per-lane `capped` (query deferred to brute kernel).
#define WALK(_cp, _b12, _i0, _DIR)                                     \
    do {                                                               \
        int _i = (_i0);                                                \
        bool _done = false;                                            \
        float4 A0, A1, A2, A3, A4, A5, A6, A7;                         \
        float4 B0, B1, B2, B3, B4, B5, B6, B7;                         \
        LOADG(A, _cp, _i);                                             \
        for (int _st = 0;;) {                                          \
            LOADG(B, _cp, _i + 8 * (_DIR));                            \
            PROC8(A, (_b12) + _i);                                     \
            {                                                          \
                float _thr = RETHR();                                  \
                float _dxe = ((_DIR) > 0) ? (A7.x - qx) : (qx - A0.x); \
                if (_dxe * _dxe >= _thr) { _done = true; break; }      \
            }                                                          \
            if (++_st >= MAXCH) break;                                 \
            _i += 8 * (_DIR);                                          \
            LOADG(A, _cp, _i + 8 * (_DIR));                            \
            PROC8(B, (_b12) + _i);                                     \
            {                                                          \
                float _thr = RETHR();                                  \
                float _dxe = ((_DIR) > 0) ? (B7.x - qx) : (qx - B0.x); \
                if (_dxe * _dxe >= _thr) { _done = true; break; }      \
            }                                                          \
            if (++_st >= MAXCH) break;                                 \
            _i += 8 * (_DIR);                                          \
        }                                                              \
        capped = capped || !_done;                                     \
    } while (0)

// Eigenvector of smallest eigenvalue of symmetric 3x3
__device__ inline void smallest_eigvec(float a00, float a01, float a02,
                                       float a11, float a12, float a22,
                                       float& vx, float& vy, float& vz) {
    float p1 = a01 * a01 + a02 * a02 + a12 * a12;
    float q = (a00 + a11 + a22) * (1.0f / 3.0f);
    float b00 = a00 - q, b11 = a11 - q, b22 = a22 - q;
    float p2 = b00 * b00 + b11 * b11 + b22 * b22 + 2.0f * p1;
    float p = sqrtf(p2 * (1.0f / 6.0f));
    if (p < 1e-20f) { vx = 1.0f; vy = 0.0f; vz = 0.0f; return; }
    float ip = 1.0f / p;
    float c00 = b00 * ip, c01 = a01 * ip, c02 = a02 * ip;
    float c11 = b11 * ip, c12 = a12 * ip, c22 = b22 * ip;
    float detB = c00 * (c11 * c22 - c12 * c12)
               - c01 * (c01 * c22 - c12 * c02)
               + c02 * (c01 * c12 - c11 * c02);
    float r = 0.5f * detB;
    r = fminf(1.0f, fmaxf(-1.0f, r));
    float phi = acosf(r) * (1.0f / 3.0f);
    float lmin = q + 2.0f * p * cosf(phi + 2.0943951023931953f);

    float m00 = a00 - lmin, m11 = a11 - lmin, m22 = a22 - lmin;
    float r0x = m00, r0y = a01, r0z = a02;
    float r1x = a01, r1y = m11, r1z = a12;
    float r2x = a02, r2y = a12, r2z = m22;
    float c0x = r0y * r1z - r0z * r1y, c0y = r0z * r1x - r0x * r1z, c0z = r0x * r1y - r0y * r1x;
    float c1x = r0y * r2z - r0z * r2y, c1y = r0z * r2x - r0x * r2z, c1z = r0x * r2y - r0y * r2x;
    float c2x = r1y * r2z - r1z * r2y, c2y = r1z * r2x - r1x * r2z, c2z = r1x * r2y - r1y * r2x;
    float n0 = c0x * c0x + c0y * c0y + c0z * c0z;
    float n1 = c1x * c1x + c1y * c1y + c1z * c1z;
    float n2 = c2x * c2x + c2y * c2y + c2z * c2z;
    float bx = c0x, by = c0y, bz = c0z, bnm = n0;
    if (n1 > bnm) { bx = c1x; by = c1y; bz = c1z; bnm = n1; }
    if (n2 > bnm) { bx = c2x; by = c2y; bz = c2z; bnm = n2; }
    if (bnm < 1e-30f) { vx = 1.0f; vy = 0.0f; vz = 0.0f; return; }
    float inv = rsqrtf(bnm);
    vx = bx * inv; vy = by * inv; vz = bz * inv;
}

// covariance of top-10 (gathered from g_spts by packed idx) -> normal -> write
__device__ inline void finish_query(int c, const float (&kq)[KNN], int orig) {
    float sx = 0.f, sy = 0.f, sz = 0.f;
    float sxx = 0.f, sxy = 0.f, sxz = 0.f;
    float syy = 0.f, syz = 0.f, szz = 0.f;
#pragma unroll
    for (int j = 0; j < KNN; ++j) {
        int p12 = (int)(__float_as_uint(kq[j]) & 0xFFFu);
        float4 nb = g_spts[c][p12 >> 10][PAD + (p12 & (LISTN - 1))];
        sx += nb.x; sy += nb.y; sz += nb.z;
        sxx = fmaf(nb.x, nb.x, sxx); sxy = fmaf(nb.x, nb.y, sxy); sxz = fmaf(nb.x, nb.z, sxz);
        syy = fmaf(nb.y, nb.y, syy); syz = fmaf(nb.y, nb.z, syz); szz = fmaf(nb.z, nb.z, szz);
    }
    const float iK = 1.0f / KNN;
    float mx = sx * iK, my = sy * iK, mz = sz * iK;
    float vx, vy, vz;
    smallest_eigvec(sxx * iK - mx * mx, sxy * iK - mx * my,
                    sxz * iK - mx * mz, syy * iK - my * my,
                    syz * iK - my * mz, szz * iK - mz * mz,
                    vx, vy, vz);
    g_nrm[(c >> 3) * BN + (c & 7) * NPTS + orig] = make_float4(vx, vy, vz, 0.f);
}

// 64 blocks (4 per cloud): bitonic sort 1024 (x, idx) pairs in LDS ->
// padded sorted float4 lists + sentinels + permutation. Block 0 also
// zeroes the output accumulator and the defer counter.
__global__ __launch_bounds__(512) void sort_lists(
    const float* __restrict__ pred, const float* __restrict__ gt,
    float* __restrict__ out) {
    __shared__ float skey[LISTN];
    __shared__ unsigned short sidx[LISTN];
    const int c = blockIdx.x >> 2;
    const int L = blockIdx.x & 3;
    const float* __restrict__ base =
        (c >= BATCH) ? (gt + (c - BATCH) * 3 * NPTS) : (pred + c * 3 * NPTS);
    const int tid = threadIdx.x;
    if (blockIdx.x == 0 && tid == 0) { out[0] = 0.0f; g_defer_cnt = 0u; }

    const int eb = L * LISTN;             // original-index base of this list
    for (int i = tid; i < LISTN; i += 512) { skey[i] = base[eb + i]; sidx[i] = (unsigned short)i; }

    for (int k = 2; k <= LISTN; k <<= 1) {
        for (int j = k >> 1; j > 0; j >>= 1) {
            __syncthreads();
            int i = ((tid / j) * 2 * j) + (tid % j);
            int p = i + j;
            bool up = ((i & k) == 0);
            float a = skey[i], b2 = skey[p];
            bool sw = up ? (a > b2) : (a < b2);
            if (sw) {
                skey[i] = b2; skey[p] = a;
                unsigned short t = sidx[i]; sidx[i] = sidx[p]; sidx[p] = t;
            }
        }
    }
    __syncthreads();

    for (int i = tid; i < LISTN; i += 512) {
        int o = eb + (int)sidx[i];
        float x = skey[i];
        float y = base[NPTS + o];
        float z = base[2 * NPTS + o];
        g_spts[c][L][PAD + i] = make_float4(x, y, z, fmaf(x, x, fmaf(y, y, z * z)));
        g_perm[c][eb + i] = (unsigned short)o;
    }
    if (tid < PAD) {   // finite sentinels: huge |dx| stops walks, huge d never inserted
        g_spts[c][L][tid]               = make_float4(-1e15f, 0.f, 0.f, 1e30f);
        g_spts[c][L][PAD + LISTN + tid] = make_float4( 1e15f, 0.f, 0.f, 1e30f);
    }
}

// One block = 64 consecutive sorted queries of list (g>>4) of cloud c.
// Wave w walks lists {2w, 2w+1}, both directions, per-lane windows with a
// hard cap; capped queries are deferred (exact recompute in knn_brute).
// Walk start via fused binary search (both lists' chains interleaved).
__global__ __launch_bounds__(128) void knn_walk() {
    __shared__ float kb[64][KNN + 2];     // wave-0 keys + capped flag

    const int g = blockIdx.x;             // 0..63
    const int c = blockIdx.y;             // 0..15
    const int lane = threadIdx.x & 63;
    const int w = threadIdx.x >> 6;
    const int qlist = g >> 4;
    const int s = (g & 15) * 64 + lane;   // sorted position in qlist
    const float4* __restrict__ cpq = &g_spts[c][qlist][PAD];
    const float4 qp = cpq[s];
    const float qx = qp.x, qw2 = qp.w;
    const float a0x = -2.0f * qp.x, a0y = -2.0f * qp.y, a0z = -2.0f * qp.z;

    const int L0 = 2 * w, L1 = 2 * w + 1;
    const float4* __restrict__ cp0 = &g_spts[c][L0][PAD];
    const float4* __restrict__ cp1 = &g_spts[c][L1][PAD];

    // lower_bound of qx in both lists (independent chains, overlapped)
    int lo0 = 0, hi0 = LISTN, lo1 = 0, hi1 = LISTN;
#pragma unroll
    for (int it = 0; it < 10; ++it) {
        int m0 = (lo0 + hi0) >> 1, m1 = (lo1 + hi1) >> 1;
        float x0 = cp0[m0].x, x1 = cp1[m1].x;
        if (x0 < qx) lo0 = m0 + 1; else hi0 = m0;
        if (x1 < qx) lo1 = m1 + 1; else hi1 = m1;
    }

    float kq[KNN];
#pragma unroll
    for (int j = 0; j < KNN; ++j) kq[j] = 1e28f;
    bool capped = false;

    WALK(cp0, L0 * LISTN, lo0 - 8, -1);   // list 2w left
    WALK(cp0, L0 * LISTN, lo0,     +1);   // list 2w right
    WALK(cp1, L1 * LISTN, lo1 - 8, -1);   // list 2w+1 left
    WALK(cp1, L1 * LISTN, lo1,     +1);   // list 2w+1 right

    if (w == 0) {
#pragma unroll
        for (int j = 0; j < KNN; ++j) kb[lane][j] = kq[j];
        kb[lane][KNN] = capped ? 1.0f : 0.0f;
    }
    __syncthreads();
    if (w == 1) {
#pragma unroll
        for (int j = 0; j < KNN; ++j) { float v = kb[lane][j]; INSERT(kq, v); }
        bool def = capped || (kb[lane][KNN] != 0.0f);
        const int orig = (int)g_perm[c][qlist * LISTN + s];
        if (def) {
            unsigned idx = atomicAdd(&g_defer_cnt, 1u);
            g_defer[idx] = ((unsigned)c << 12) | (unsigned)orig;
        } else {
            finish_query(c, kq, orig);
        }
    }
}

// exact cleanup: one wave per deferred query; 64 cands/lane over the 4
// lists (coalesced), butterfly shfl_xor merge of per-lane top-10s
__global__ __launch_bounds__(256) void knn_brute(
    const float* __restrict__ pred, const float* __restrict__ gt) {
    const int lane = threadIdx.x & 63;
    const int wid = blockIdx.x * 4 + (threadIdx.x >> 6);
    const unsigned cnt = g_defer_cnt;
    for (unsigned u = wid; u < cnt; u += 1024) {
        const unsigned e = g_defer[u];
        const int c = (int)(e >> 12), orig = (int)(e & 0xFFFu);
        const float* __restrict__ base =
            (c >= BATCH) ? (gt + (c - BATCH) * 3 * NPTS) : (pred + c * 3 * NPTS);
        const float qxv = base[orig], qyv = base[NPTS + orig], qzv = base[2 * NPTS + orig];
        const float a0x = -2.0f * qxv, a0y = -2.0f * qyv, a0z = -2.0f * qzv;

        float kq[KNN];
#pragma unroll
        for (int j = 0; j < KNN; ++j) kq[j] = 1e28f;
#pragma unroll
        for (int L = 0; L < NLIST; ++L) {
#pragma unroll
            for (int r = 0; r < LISTN / 64; ++r) {
                int pos = r * 64 + lane;
                float4 p4 = g_spts[c][L][PAD + pos];
                PROC1(p4, L * LISTN + pos);
            }
        }
        // 64-lane butterfly merge: read partner's 10 keys first, then insert
#pragma unroll
        for (int off = 32; off >= 1; off >>= 1) {
            float tmp[KNN];
#pragma unroll
            for (int j = 0; j < KNN; ++j) tmp[j] = __shfl_xor(kq[j], off);
#pragma unroll
            for (int j = 0; j < KNN; ++j) INSERT(kq, tmp[j]);
        }
        if (lane == 0) finish_query(c, kq, orig);
    }
}

// loss over 32768 point pairs; one wave-sum atomic per 64 lanes
__global__ __launch_bounds__(256) void cos_loss_kernel(float* __restrict__ out) {
    const int i = blockIdx.x * 256 + threadIdx.x;     // grid sized exactly BN
    float4 p = g_nrm[i];
    float4 g = g_nrm[BN + i];
    float dot = p.x * g.x + p.y * g.y + p.z * g.z;
    float npn = sqrtf(p.x * p.x + p.y * p.y + p.z * p.z);
    float ngn = sqrtf(g.x * g.x + g.y * g.y + g.z * g.z);
    float acc = 1.0f - fabsf(dot / fmaxf(npn * ngn, 1e-8f));
    for (int off = 32; off > 0; off >>= 1) acc += __shfl_down(acc, off);
    if ((threadIdx.x & 63) == 0) atomicAdd(out, acc * (1.0f / (float)BN));
}

extern "C" void kernel_launch(void* const* d_in, const int* in_sizes, int n_in,
                              void* d_out, int out_size, void* d_ws, size_t ws_size,
                              hipStream_t stream) {
    const float* pred = (const float*)d_in[0];
    const float* gt = (const float*)d_in[1];
    float* out = (float*)d_out;

    sort_lists<<<dim3(NCLOUD * NLIST), 512, 0, stream>>>(pred, gt, out);
    knn_walk<<<dim3(64, NCLOUD), 128, 0, stream>>>();
    knn_brute<<<dim3(256), 256, 0, stream>>>(pred, gt);
    cos_loss_kernel<<<dim3(BN / 256), 256, 0, stream>>>(out);
}

// Round 8
// 347.419 us; speedup vs baseline: 1.3207x; 1.3207x over previous
//
#include <hip/hip_runtime.h>
#include <float.h>
#include <math.h>

#define BATCH 8
#define NPTS 4096
#define KNN 10
#define BN (BATCH * NPTS)          // 32768 points per cloud
#define NCLOUD (2 * BATCH)         // 16 clouds
#define NLIST 4                    // sorted sub-lists per cloud
#define LISTN (NPTS / NLIST)       // 1024 elements per list
#define PAD 32                     // sentinel guard band each side (covers prefetch)
#define LSTRIDE (LISTN + 2 * PAD)
#define MAXCH 16                   // cap: 8-candidate chunks per direction beyond seed

__device__ float4 g_spts[NCLOUD][NLIST][LSTRIDE]; // sorted (x,y,z,|p|^2)+guards
__device__ unsigned short g_perm[NCLOUD][NPTS];   // [list*1024+pos] -> orig idx
__device__ float4 g_nrm[2 * BN];                  // normals, original order
__device__ unsigned g_defer[NCLOUD * NPTS];       // (cloud<<12)|orig
__device__ unsigned g_defer_cnt;

__device__ inline float med3f(float x, float a, float b) {
    return __builtin_amdgcn_fmed3f(x, a, b);
}

// branchless sorted insert of key into ascending k[0..9] (drop largest)
#define INSERT(karr, key)                                              \
    do {                                                               \
        _Pragma("unroll")                                              \
        for (int _j = KNN - 1; _j >= 1; --_j)                          \
            karr[_j] = med3f((key), karr[_j - 1], karr[_j]);           \
        karr[0] = fminf((key), karr[0]);                               \
    } while (0)

// distance + pack(list*1024+pos, 12b) + insert; guards have w=1e30 ->
// d ~1e30 (finite), never beats the 1e28 init -> junk idx never selected
#define PROC1(_p, _pos12)                                              \
    do {                                                               \
        float _d = fmaf((_p).z, a0z, fmaf((_p).y, a0y, fmaf((_p).x, a0x, (_p).w))); \
        float _k = __uint_as_float((__float_as_uint(_d) & 0xFFFFF000u) | ((unsigned)(_pos12) & 0xFFFu)); \
        INSERT(kq, _k);                                                \
    } while (0)

#define PROC8(P, _b)                                                   \
    do {                                                               \
        PROC1(P##0, (_b) + 0); PROC1(P##1, (_b) + 1);                  \
        PROC1(P##2, (_b) + 2); PROC1(P##3, (_b) + 3);                  \
        PROC1(P##4, (_b) + 4); PROC1(P##5, (_b) + 5);                  \
        PROC1(P##6, (_b) + 6); PROC1(P##7, (_b) + 7);                  \
    } while (0)

#define LOADG(P, _cp, _i)                                              \
    do {                                                               \
        P##0 = (_cp)[(_i) + 0]; P##1 = (_cp)[(_i) + 1];                \
        P##2 = (_cp)[(_i) + 2]; P##3 = (_cp)[(_i) + 3];                \
        P##4 = (_cp)[(_i) + 4]; P##5 = (_cp)[(_i) + 5];                \
        P##6 = (_cp)[(_i) + 6]; P##7 = (_cp)[(_i) + 7];                \
    } while (0)

// conservative d10^2 bound from a 10th-best key value v (+ margin for the
// 12-bit key truncation); any stop decision using a thr >= final d10^2 is exact
#define THRV(_v) ((_v) + qw2 + fmaf(fabsf((_v)), 2e-3f, 1e-4f))
#define RETHR()  THRV(kq[KNN - 1])

// one seed chunk (no prefetch)
#define SEEDC(_cp, _b12, _i)                                           \
    do {                                                               \
        float4 S0, S1, S2, S3, S4, S5, S6, S7;                         \
        LOADG(S, _cp, _i);                                             \
        PROC8(S, (_b12) + (_i));                                       \
    } while (0)

// capped window walk, one direction; A/B register double-buffer.
// Break uses min(own running thr, union-seed thrU) — both >= final d10^2.
// Sentinel chunks (|x|=1e15) always satisfy the break, bounding guard reads.
#define WALK(_cp, _b12, _i0, _DIR)                                     \
    do {                                                               \
        int _i = (_i0);                                                \
        bool _done = false;                                            \
        float4 A0, A1, A2, A3, A4, A5, A6, A7;                         \
        float4 B0, B1, B2, B3, B4, B5, B6, B7;                         \
        LOADG(A, _cp, _i);                                             \
        for (int _st = 0;;) {                                          \
            LOADG(B, _cp, _i + 8 * (_DIR));                            \
            PROC8(A, (_b12) + _i);                                     \
            {                                                          \
                float _thr = fminf(RETHR(), thrU);                     \
                float _dxe = ((_DIR) > 0) ? (A7.x - qx) : (qx - A0.x); \
                if (_dxe * _dxe >= _thr) { _done = true; break; }      \
            }                                                          \
            if (++_st >= MAXCH) break;                                 \
            _i += 8 * (_DIR);                                          \
            LOADG(A, _cp, _i + 8 * (_DIR));                            \
            PROC8(B, (_b12) + _i);                                     \
            {                                                          \
                float _thr = fminf(RETHR(), thrU);                     \
                float _dxe = ((_DIR) > 0) ? (B7.x - qx) : (qx - B0.x); \
                if (_dxe * _dxe >= _thr) { _done = true; break; }      \
            }                                                          \
            if (++_st >= MAXCH) break;                                 \
            _i += 8 * (_DIR);                                          \
        }                                                              \
        capped = capped || !_done;                                     \
    } while (0)

// Eigenvector of smallest eigenvalue of symmetric 3x3
__device__ inline void smallest_eigvec(float a00, float a01, float a02,
                                       float a11, float a12, float a22,
                                       float& vx, float& vy, float& vz) {
    float p1 = a01 * a01 + a02 * a02 + a12 * a12;
    float q = (a00 + a11 + a22) * (1.0f / 3.0f);
    float b00 = a00 - q, b11 = a11 - q, b22 = a22 - q;
    float p2 = b00 * b00 + b11 * b11 + b22 * b22 + 2.0f * p1;
    float p = sqrtf(p2 * (1.0f / 6.0f));
    if (p < 1e-20f) { vx = 1.0f; vy = 0.0f; vz = 0.0f; return; }
    float ip = 1.0f / p;
    float c00 = b00 * ip, c01 = a01 * ip, c02 = a02 * ip;
    float c11 = b11 * ip, c12 = a12 * ip, c22 = b22 * ip;
    float detB = c00 * (c11 * c22 - c12 * c12)
               - c01 * (c01 * c22 - c12 * c02)
               + c02 * (c01 * c12 - c11 * c02);
    float r = 0.5f * detB;
    r = fminf(1.0f, fmaxf(-1.0f, r));
    float phi = acosf(r) * (1.0f / 3.0f);
    float lmin = q + 2.0f * p * cosf(phi + 2.0943951023931953f);

    float m00 = a00 - lmin, m11 = a11 - lmin, m22 = a22 - lmin;
    float r0x = m00, r0y = a01, r0z = a02;
    float r1x = a01, r1y = m11, r1z = a12;
    float r2x = a02, r2y = a12, r2z = m22;
    float c0x = r0y * r1z - r0z * r1y, c0y = r0z * r1x - r0x * r1z, c0z = r0x * r1y - r0y * r1x;
    float c1x = r0y * r2z - r0z * r2y, c1y = r0z * r2x - r0x * r2z, c1z = r0x * r2y - r0y * r2x;
    float c2x = r1y * r2z - r1z * r2y, c2y = r1z * r2x - r1x * r2z, c2z = r1x * r2y - r1y * r2x;
    float n0 = c0x * c0x + c0y * c0y + c0z * c0z;
    float n1 = c1x * c1x + c1y * c1y + c1z * c1z;
    float n2 = c2x * c2x + c2y * c2y + c2z * c2z;
    float bx = c0x, by = c0y, bz = c0z, bnm = n0;
    if (n1 > bnm) { bx = c1x; by = c1y; bz = c1z; bnm = n1; }
    if (n2 > bnm) { bx = c2x; by = c2y; bz = c2z; bnm = n2; }
    if (bnm < 1e-30f) { vx = 1.0f; vy = 0.0f; vz = 0.0f; return; }
    float inv = rsqrtf(bnm);
    vx = bx * inv; vy = by * inv; vz = bz * inv;
}

// covariance of top-10 (gathered from g_spts by packed idx) -> normal -> write
__device__ inline void finish_query(int c, const float (&kq)[KNN], int orig) {
    float sx = 0.f, sy = 0.f, sz = 0.f;
    float sxx = 0.f, sxy = 0.f, sxz = 0.f;
    float syy = 0.f, syz = 0.f, szz = 0.f;
#pragma unroll
    for (int j = 0; j < KNN; ++j) {
        int p12 = (int)(__float_as_uint(kq[j]) & 0xFFFu);
        float4 nb = g_spts[c][p12 >> 10][PAD + (p12 & (LISTN - 1))];
        sx += nb.x; sy += nb.y; sz += nb.z;
        sxx = fmaf(nb.x, nb.x, sxx); sxy = fmaf(nb.x, nb.y, sxy); sxz = fmaf(nb.x, nb.z, sxz);
        syy = fmaf(nb.y, nb.y, syy); syz = fmaf(nb.y, nb.z, syz); szz = fmaf(nb.z, nb.z, szz);
    }
    const float iK = 1.0f / KNN;
    float mx = sx * iK, my = sy * iK, mz = sz * iK;
    float vx, vy, vz;
    smallest_eigvec(sxx * iK - mx * mx, sxy * iK - mx * my,
                    sxz * iK - mx * mz, syy * iK - my * my,
                    syz * iK - my * mz, szz * iK - mz * mz,
                    vx, vy, vz);
    g_nrm[(c >> 3) * BN + (c & 7) * NPTS + orig] = make_float4(vx, vy, vz, 0.f);
}

// 64 blocks (4 per cloud): bitonic sort 1024 (x, idx) pairs in LDS ->
// padded sorted float4 lists + sentinels + permutation
__global__ __launch_bounds__(512) void sort_lists(
    const float* __restrict__ pred, const float* __restrict__ gt,
    float* __restrict__ out) {
    __shared__ float skey[LISTN];
    __shared__ unsigned short sidx[LISTN];
    const int c = blockIdx.x >> 2;
    const int L = blockIdx.x & 3;
    const float* __restrict__ base =
        (c >= BATCH) ? (gt + (c - BATCH) * 3 * NPTS) : (pred + c * 3 * NPTS);
    const int tid = threadIdx.x;
    if (blockIdx.x == 0 && tid == 0) { out[0] = 0.0f; g_defer_cnt = 0u; }

    const int eb = L * LISTN;             // original-index base of this list
    for (int i = tid; i < LISTN; i += 512) { skey[i] = base[eb + i]; sidx[i] = (unsigned short)i; }

    for (int k = 2; k <= LISTN; k <<= 1) {
        for (int j = k >> 1; j > 0; j >>= 1) {
            __syncthreads();
            int i = ((tid / j) * 2 * j) + (tid % j);
            int p = i + j;
            bool up = ((i & k) == 0);
            float a = skey[i], b2 = skey[p];
            bool sw = up ? (a > b2) : (a < b2);
            if (sw) {
                skey[i] = b2; skey[p] = a;
                unsigned short t = sidx[i]; sidx[i] = sidx[p]; sidx[p] = t;
            }
        }
    }
    __syncthreads();

    for (int i = tid; i < LISTN; i += 512) {
        int o = eb + (int)sidx[i];
        float x = skey[i];
        float y = base[NPTS + o];
        float z = base[2 * NPTS + o];
        g_spts[c][L][PAD + i] = make_float4(x, y, z, fmaf(x, x, fmaf(y, y, z * z)));
        g_perm[c][eb + i] = (unsigned short)o;
    }
    if (tid < PAD) {   // finite sentinels: huge |dx| stops walks, huge d never inserted
        g_spts[c][L][tid]               = make_float4(-1e15f, 0.f, 0.f, 1e30f);
        g_spts[c][L][PAD + LISTN + tid] = make_float4( 1e15f, 0.f, 0.f, 1e30f);
    }
}

// One block = 64 consecutive sorted queries of list (g>>4) of cloud c.
// 4 waves: wave w owns list w (binary search + 16-candidate seed + both
// walks). Seeds are published to LDS -> every wave computes thrU = d10^2
// bound of the 64-candidate UNION before walking (the round-7 fix: walks
// start with a near-final threshold, so the exact dx^2 break fires in
// ~10 chunks and the cap/defer path is reserved for true 3D outliers).
// Final 4-way merge is duplicate-free (lists are disjoint).
__global__ __launch_bounds__(256) void knn_walk() {
    __shared__ float kb[NLIST][64][KNN + 3];  // stride 13 (odd): conflict-free

    const int g = blockIdx.x;             // 0..63
    const int c = blockIdx.y;             // 0..15
    const int lane = threadIdx.x & 63;
    const int w = threadIdx.x >> 6;       // wave = list 0..3
    const int qlist = g >> 4;
    const int s = (g & 15) * 64 + lane;   // sorted position in qlist
    const float4 qp = g_spts[c][qlist][PAD + s];
    const float qx = qp.x, qw2 = qp.w;
    const float a0x = -2.0f * qp.x, a0y = -2.0f * qp.y, a0z = -2.0f * qp.z;

    const float4* __restrict__ cp = &g_spts[c][w][PAD];
    const int b12 = w * LISTN;

    // lower_bound of qx in list w
    int lo = 0, hi = LISTN;
#pragma unroll
    for (int it = 0; it < 10; ++it) {
        int m = (lo + hi) >> 1;
        if (cp[m].x < qx) lo = m + 1; else hi = m;
    }

    float kq[KNN];
#pragma unroll
    for (int j = 0; j < KNN; ++j) kq[j] = 1e28f;

    // seed: the 16 x-nearest candidates of this list
    SEEDC(cp, b12, lo - 8);
    SEEDC(cp, b12, lo);

    // publish seeds, build union threshold
#pragma unroll
    for (int j = 0; j < KNN; ++j) kb[w][lane][j] = kq[j];
    __syncthreads();
    float thrU;
    {
        float tmp[KNN];
#pragma unroll
        for (int j = 0; j < KNN; ++j) tmp[j] = kq[j];
#pragma unroll
        for (int ow = 1; ow < NLIST; ++ow) {
            const int o = (w + ow) & 3;
#pragma unroll
            for (int j = 0; j < KNN; ++j) { float v = kb[o][lane][j]; INSERT(tmp, v); }
        }
        thrU = THRV(tmp[KNN - 1]);
    }

    bool capped = false;
    WALK(cp, b12, lo - 16, -1);
    WALK(cp, b12, lo + 8, +1);

    __syncthreads();   // seed reads done everywhere before final overwrite
#pragma unroll
    for (int j = 0; j < KNN; ++j) kb[w][lane][j] = kq[j];
    kb[w][lane][KNN] = capped ? 1.0f : 0.0f;
    __syncthreads();

    if (w == 0) {
        bool def = capped;
#pragma unroll
        for (int ow = 1; ow < NLIST; ++ow) {
#pragma unroll
            for (int j = 0; j < KNN; ++j) { float v = kb[ow][lane][j]; INSERT(kq, v); }
            def = def || (kb[ow][lane][KNN] != 0.0f);
        }
        const int orig = (int)g_perm[c][qlist * LISTN + s];
        if (def) {
            unsigned idx = atomicAdd(&g_defer_cnt, 1u);
            g_defer[idx] = ((unsigned)c << 12) | (unsigned)orig;
        } else {
            finish_query(c, kq, orig);
        }
    }
}

// exact cleanup: one wave per deferred query (grid-stride over 8192 waves);
// 64 cands/lane over the 4 lists, butterfly shfl_xor merge of top-10s
__global__ __launch_bounds__(256) void knn_brute(
    const float* __restrict__ pred, const float* __restrict__ gt) {
    const int lane = threadIdx.x & 63;
    const int wid = blockIdx.x * 4 + (threadIdx.x >> 6);
    const unsigned cnt = g_defer_cnt;
    for (unsigned u = wid; u < cnt; u += 8192) {
        const unsigned e = g_defer[u];
        const int c = (int)(e >> 12), orig = (int)(e & 0xFFFu);
        const float* __restrict__ base =
            (c >= BATCH) ? (gt + (c - BATCH) * 3 * NPTS) : (pred + c * 3 * NPTS);
        const float qxv = base[orig], qyv = base[NPTS + orig], qzv = base[2 * NPTS + orig];
        const float a0x = -2.0f * qxv, a0y = -2.0f * qyv, a0z = -2.0f * qzv;

        float kq[KNN];
#pragma unroll
        for (int j = 0; j < KNN; ++j) kq[j] = 1e28f;
#pragma unroll
        for (int L = 0; L < NLIST; ++L) {
#pragma unroll
            for (int r = 0; r < LISTN / 64; ++r) {
                int pos = r * 64 + lane;
                float4 p4 = g_spts[c][L][PAD + pos];
                PROC1(p4, L * LISTN + pos);
            }
        }
#pragma unroll
        for (int off = 32; off >= 1; off >>= 1) {
            float tmp[KNN];
#pragma unroll
            for (int j = 0; j < KNN; ++j) tmp[j] = __shfl_xor(kq[j], off);
#pragma unroll
            for (int j = 0; j < KNN; ++j) INSERT(kq, tmp[j]);
        }
        if (lane == 0) finish_query(c, kq, orig);
    }
}

// loss over 32768 point pairs; one wave-sum atomic per 64 lanes
__global__ __launch_bounds__(256) void cos_loss_kernel(float* __restrict__ out) {
    const int i = blockIdx.x * 256 + threadIdx.x;     // grid sized exactly BN
    float4 p = g_nrm[i];
    float4 g = g_nrm[BN + i];
    float dot = p.x * g.x + p.y * g.y + p.z * g.z;
    float npn = sqrtf(p.x * p.x + p.y * p.y + p.z * p.z);
    float ngn = sqrtf(g.x * g.x + g.y * g.y + g.z * g.z);
    float acc = 1.0f - fabsf(dot / fmaxf(npn * ngn, 1e-8f));
    for (int off = 32; off > 0; off >>= 1) acc += __shfl_down(acc, off);
    if ((threadIdx.x & 63) == 0) atomicAdd(out, acc * (1.0f / (float)BN));
}

extern "C" void kernel_launch(void* const* d_in, const int* in_sizes, int n_in,
                              void* d_out, int out_size, void* d_ws, size_t ws_size,
                              hipStream_t stream) {
    const float* pred = (const float*)d_in[0];
    const float* gt = (const float*)d_in[1];
    float* out = (float*)d_out;

    sort_lists<<<dim3(NCLOUD * NLIST), 512, 0, stream>>>(pred, gt, out);
    knn_walk<<<dim3(64, NCLOUD), 256, 0, stream>>>();
    knn_brute<<<dim3(2048), 256, 0, stream>>>(pred, gt);
    cos_loss_kernel<<<dim3(BN / 256), 256, 0, stream>>>(out);
}

// Round 9
// 182.452 us; speedup vs baseline: 2.5148x; 1.9042x over previous
//
#include <hip/hip_runtime.h>
#include <float.h>
#include <math.h>

#define BATCH 8
#define NPTS 4096
#define KNN 10
#define BN (BATCH * NPTS)          // 32768 points per cloud
#define NCLOUD (2 * BATCH)         // 16 clouds
#define NLIST 4                    // sorted sub-lists per cloud
#define LISTN (NPTS / NLIST)       // 1024 elements per list
#define PAD 32                     // sentinel guard band each side (covers prefetch)
#define LSTRIDE (LISTN + 2 * PAD)
#define PH_A 6                     // phase-A chunks per direction (pre-exchange)
#define PH_B 18                    // phase-B chunks per direction (post-exchange)

__device__ float4 g_spts[NCLOUD][NLIST][LSTRIDE]; // sorted (x,y,z,|p|^2)+guards
__device__ unsigned short g_perm[NCLOUD][NPTS];   // [list*1024+pos] -> orig idx
__device__ float4 g_nrm[2 * BN];                  // normals, original order
__device__ unsigned g_defer[NCLOUD * NPTS];       // (cloud<<12)|orig
__device__ unsigned g_defer_cnt;

__device__ inline float med3f(float x, float a, float b) {
    return __builtin_amdgcn_fmed3f(x, a, b);
}

// branchless sorted insert of key into ascending k[0..9] (drop largest)
#define INSERT(karr, key)                                              \
    do {                                                               \
        _Pragma("unroll")                                              \
        for (int _j = KNN - 1; _j >= 1; --_j)                          \
            karr[_j] = med3f((key), karr[_j - 1], karr[_j]);           \
        karr[0] = fminf((key), karr[0]);                               \
    } while (0)

// distance + pack(list*1024+pos, 12b) + insert; guards have w=1e30 ->
// d ~1e30 (finite), never beats the 1e28 init -> junk idx never selected
#define PROC1(_p, _pos12)                                              \
    do {                                                               \
        float _d = fmaf((_p).z, a0z, fmaf((_p).y, a0y, fmaf((_p).x, a0x, (_p).w))); \
        float _k = __uint_as_float((__float_as_uint(_d) & 0xFFFFF000u) | ((unsigned)(_pos12) & 0xFFFu)); \
        INSERT(kq, _k);                                                \
    } while (0)

#define PROC8(P, _b)                                                   \
    do {                                                               \
        PROC1(P##0, (_b) + 0); PROC1(P##1, (_b) + 1);                  \
        PROC1(P##2, (_b) + 2); PROC1(P##3, (_b) + 3);                  \
        PROC1(P##4, (_b) + 4); PROC1(P##5, (_b) + 5);                  \
        PROC1(P##6, (_b) + 6); PROC1(P##7, (_b) + 7);                  \
    } while (0)

#define LOADG(P, _cp, _i)                                              \
    do {                                                               \
        P##0 = (_cp)[(_i) + 0]; P##1 = (_cp)[(_i) + 1];                \
        P##2 = (_cp)[(_i) + 2]; P##3 = (_cp)[(_i) + 3];                \
        P##4 = (_cp)[(_i) + 4]; P##5 = (_cp)[(_i) + 5];                \
        P##6 = (_cp)[(_i) + 6]; P##7 = (_cp)[(_i) + 7];                \
    } while (0)

// conservative d10^2 bound from a 10th-best key value v (+ margin for the
// 12-bit key truncation); any stop using a thr >= final d10^2 is exact
#define THRV(_v) ((_v) + qw2 + fmaf(fabsf((_v)), 2e-3f, 1e-4f))
#define RETHR()  THRV(kq[KNN - 1])

// one seed chunk (no prefetch)
#define SEEDC(_cp, _b12, _i)                                           \
    do {                                                               \
        float4 S0, S1, S2, S3, S4, S5, S6, S7;                         \
        LOADG(S, _cp, _i);                                             \
        PROC8(S, (_b12) + (_i));                                       \
    } while (0)

// resumable capped walk, one direction, single-ahead prefetch.
// Break uses min(own running bound, shared union bound thrU) — both are
// >= final d10^2 at all times => exact. Sentinels (|x|=1e15) always fire
// the break => walks terminate at list ends; prefetch stays inside PAD.
template <int DIR>
__device__ __forceinline__ void walk_dir(
    const float4* __restrict__ cp, int b12, int& i, bool& done,
    float (&kq)[KNN], float qx, float qw2, float thrU,
    float a0x, float a0y, float a0z, int maxch) {
    if (done) return;
    float4 A0, A1, A2, A3, A4, A5, A6, A7;
    LOADG(A, cp, i);
    for (int st = 0; st < maxch; ++st) {
        float4 B0, B1, B2, B3, B4, B5, B6, B7;
        LOADG(B, cp, i + 8 * DIR);
        PROC8(A, b12 + i);
        float thr = fminf(RETHR(), thrU);
        float dxe = (DIR > 0) ? (A7.x - qx) : (qx - A0.x);
        if (dxe * dxe >= thr) { done = true; return; }
        i += 8 * DIR;
        A0 = B0; A1 = B1; A2 = B2; A3 = B3;
        A4 = B4; A5 = B5; A6 = B6; A7 = B7;
    }
}

// Eigenvector of smallest eigenvalue of symmetric 3x3
__device__ inline void smallest_eigvec(float a00, float a01, float a02,
                                       float a11, float a12, float a22,
                                       float& vx, float& vy, float& vz) {
    float p1 = a01 * a01 + a02 * a02 + a12 * a12;
    float q = (a00 + a11 + a22) * (1.0f / 3.0f);
    float b00 = a00 - q, b11 = a11 - q, b22 = a22 - q;
    float p2 = b00 * b00 + b11 * b11 + b22 * b22 + 2.0f * p1;
    float p = sqrtf(p2 * (1.0f / 6.0f));
    if (p < 1e-20f) { vx = 1.0f; vy = 0.0f; vz = 0.0f; return; }
    float ip = 1.0f / p;
    float c00 = b00 * ip, c01 = a01 * ip, c02 = a02 * ip;
    float c11 = b11 * ip, c12 = a12 * ip, c22 = b22 * ip;
    float detB = c00 * (c11 * c22 - c12 * c12)
               - c01 * (c01 * c22 - c12 * c02)
               + c02 * (c01 * c12 - c11 * c02);
    float r = 0.5f * detB;
    r = fminf(1.0f, fmaxf(-1.0f, r));
    float phi = acosf(r) * (1.0f / 3.0f);
    float lmin = q + 2.0f * p * cosf(phi + 2.0943951023931953f);

    float m00 = a00 - lmin, m11 = a11 - lmin, m22 = a22 - lmin;
    float r0x = m00, r0y = a01, r0z = a02;
    float r1x = a01, r1y = m11, r1z = a12;
    float r2x = a02, r2y = a12, r2z = m22;
    float c0x = r0y * r1z - r0z * r1y, c0y = r0z * r1x - r0x * r1z, c0z = r0x * r1y - r0y * r1x;
    float c1x = r0y * r2z - r0z * r2y, c1y = r0z * r2x - r0x * r2z, c1z = r0x * r2y - r0y * r2x;
    float c2x = r1y * r2z - r1z * r2y, c2y = r1z * r2x - r1x * r2z, c2z = r1x * r2y - r1y * r2x;
    float n0 = c0x * c0x + c0y * c0y + c0z * c0z;
    float n1 = c1x * c1x + c1y * c1y + c1z * c1z;
    float n2 = c2x * c2x + c2y * c2y + c2z * c2z;
    float bx = c0x, by = c0y, bz = c0z, bnm = n0;
    if (n1 > bnm) { bx = c1x; by = c1y; bz = c1z; bnm = n1; }
    if (n2 > bnm) { bx = c2x; by = c2y; bz = c2z; bnm = n2; }
    if (bnm < 1e-30f) { vx = 1.0f; vy = 0.0f; vz = 0.0f; return; }
    float inv = rsqrtf(bnm);
    vx = bx * inv; vy = by * inv; vz = bz * inv;
}

// covariance of top-10 (gathered from g_spts by packed idx) -> normal -> write
__device__ inline void finish_query(int c, const float (&kq)[KNN], int orig) {
    float sx = 0.f, sy = 0.f, sz = 0.f;
    float sxx = 0.f, sxy = 0.f, sxz = 0.f;
    float syy = 0.f, syz = 0.f, szz = 0.f;
#pragma unroll
    for (int j = 0; j < KNN; ++j) {
        int p12 = (int)(__float_as_uint(kq[j]) & 0xFFFu);
        float4 nb = g_spts[c][p12 >> 10][PAD + (p12 & (LISTN - 1))];
        sx += nb.x; sy += nb.y; sz += nb.z;
        sxx = fmaf(nb.x, nb.x, sxx); sxy = fmaf(nb.x, nb.y, sxy); sxz = fmaf(nb.x, nb.z, sxz);
        syy = fmaf(nb.y, nb.y, syy); syz = fmaf(nb.y, nb.z, syz); szz = fmaf(nb.z, nb.z, szz);
    }
    const float iK = 1.0f / KNN;
    float mx = sx * iK, my = sy * iK, mz = sz * iK;
    float vx, vy, vz;
    smallest_eigvec(sxx * iK - mx * mx, sxy * iK - mx * my,
                    sxz * iK - mx * mz, syy * iK - my * my,
                    syz * iK - my * mz, szz * iK - mz * mz,
                    vx, vy, vz);
    g_nrm[(c >> 3) * BN + (c & 7) * NPTS + orig] = make_float4(vx, vy, vz, 0.f);
}

// 64 blocks (4 per cloud): bitonic sort 1024 (x, idx) pairs in LDS ->
// padded sorted float4 lists + sentinels + permutation
__global__ __launch_bounds__(512) void sort_lists(
    const float* __restrict__ pred, const float* __restrict__ gt,
    float* __restrict__ out) {
    __shared__ float skey[LISTN];
    __shared__ unsigned short sidx[LISTN];
    const int c = blockIdx.x >> 2;
    const int L = blockIdx.x & 3;
    const float* __restrict__ base =
        (c >= BATCH) ? (gt + (c - BATCH) * 3 * NPTS) : (pred + c * 3 * NPTS);
    const int tid = threadIdx.x;
    if (blockIdx.x == 0 && tid == 0) { out[0] = 0.0f; g_defer_cnt = 0u; }

    const int eb = L * LISTN;             // original-index base of this list
    for (int i = tid; i < LISTN; i += 512) { skey[i] = base[eb + i]; sidx[i] = (unsigned short)i; }

    for (int k = 2; k <= LISTN; k <<= 1) {
        for (int j = k >> 1; j > 0; j >>= 1) {
            __syncthreads();
            int i = ((tid / j) * 2 * j) + (tid % j);
            int p = i + j;
            bool up = ((i & k) == 0);
            float a = skey[i], b2 = skey[p];
            bool sw = up ? (a > b2) : (a < b2);
            if (sw) {
                skey[i] = b2; skey[p] = a;
                unsigned short t = sidx[i]; sidx[i] = sidx[p]; sidx[p] = t;
            }
        }
    }
    __syncthreads();

    for (int i = tid; i < LISTN; i += 512) {
        int o = eb + (int)sidx[i];
        float x = skey[i];
        float y = base[NPTS + o];
        float z = base[2 * NPTS + o];
        g_spts[c][L][PAD + i] = make_float4(x, y, z, fmaf(x, x, fmaf(y, y, z * z)));
        g_perm[c][eb + i] = (unsigned short)o;
    }
    if (tid < PAD) {   // finite sentinels: huge |dx| stops walks, huge d never inserted
        g_spts[c][L][tid]               = make_float4(-1e15f, 0.f, 0.f, 1e30f);
        g_spts[c][L][PAD + LISTN + tid] = make_float4( 1e15f, 0.f, 0.f, 1e30f);
    }
}

// One block = 64 consecutive sorted queries of list (g>>4) of cloud c.
// 4 waves, one list each. Two-phase walk with a mid-walk threshold exchange:
//   seed (16 x-nearest per list) -> union thrU1
//   phase A: 6 chunks/direction  -> publish running top-10s
//   thrU2 = union d10 bound (~true global d10)
//   phase B: resume, 18 chunks/direction with tight thrU2
// All thresholds are conservative (>= final d10^2) => prune exact.
// Residual capped queries (3D outliers at central x) defer to knn_brute.
__global__ __launch_bounds__(256) void knn_walk() {
    __shared__ float kb[NLIST][64][KNN + 3];  // stride 13 (odd): conflict-free

    const int g = blockIdx.x;             // 0..63
    const int c = blockIdx.y;             // 0..15
    const int lane = threadIdx.x & 63;
    const int w = threadIdx.x >> 6;       // wave = list 0..3
    const int qlist = g >> 4;
    const int s = (g & 15) * 64 + lane;   // sorted position in qlist
    const float4 qp = g_spts[c][qlist][PAD + s];
    const float qx = qp.x, qw2 = qp.w;
    const float a0x = -2.0f * qp.x, a0y = -2.0f * qp.y, a0z = -2.0f * qp.z;

    const float4* __restrict__ cp = &g_spts[c][w][PAD];
    const int b12 = w * LISTN;

    // lower_bound of qx in list w
    int lo = 0, hi = LISTN;
#pragma unroll
    for (int it = 0; it < 10; ++it) {
        int m = (lo + hi) >> 1;
        if (cp[m].x < qx) lo = m + 1; else hi = m;
    }

    float kq[KNN];
#pragma unroll
    for (int j = 0; j < KNN; ++j) kq[j] = 1e28f;

    // seed: the 16 x-nearest candidates of this list
    SEEDC(cp, b12, lo - 8);
    SEEDC(cp, b12, lo);

    // publish seeds, build union threshold 1
#pragma unroll
    for (int j = 0; j < KNN; ++j) kb[w][lane][j] = kq[j];
    __syncthreads();
    float thrU;
    {
        float tmp[KNN];
#pragma unroll
        for (int j = 0; j < KNN; ++j) tmp[j] = kq[j];
#pragma unroll
        for (int ow = 1; ow < NLIST; ++ow) {
            const int o = (w + ow) & 3;
#pragma unroll
            for (int j = 0; j < KNN; ++j) { float v = kb[o][lane][j]; INSERT(tmp, v); }
        }
        thrU = THRV(tmp[KNN - 1]);
    }

    int iL = lo - 16, iR = lo + 8;
    bool doneL = false, doneR = false;

    // phase A (short: fill the running top-10s near the query)
    walk_dir<-1>(cp, b12, iL, doneL, kq, qx, qw2, thrU, a0x, a0y, a0z, PH_A);
    walk_dir<+1>(cp, b12, iR, doneR, kq, qx, qw2, thrU, a0x, a0y, a0z, PH_A);

    // exchange: rebuild union threshold from running top-10s (~ true d10)
    __syncthreads();   // every wave consumed thrU1 before kb is overwritten
#pragma unroll
    for (int j = 0; j < KNN; ++j) kb[w][lane][j] = kq[j];
    __syncthreads();
    {
        float tmp[KNN];
#pragma unroll
        for (int j = 0; j < KNN; ++j) tmp[j] = kq[j];
#pragma unroll
        for (int ow = 1; ow < NLIST; ++ow) {
            const int o = (w + ow) & 3;
#pragma unroll
            for (int j = 0; j < KNN; ++j) { float v = kb[o][lane][j]; INSERT(tmp, v); }
        }
        thrU = THRV(tmp[KNN - 1]);
    }

    // phase B (tight threshold -> break fires at ~the true window edge)
    walk_dir<-1>(cp, b12, iL, doneL, kq, qx, qw2, thrU, a0x, a0y, a0z, PH_B);
    walk_dir<+1>(cp, b12, iR, doneR, kq, qx, qw2, thrU, a0x, a0y, a0z, PH_B);
    const bool capped = !(doneL && doneR);

    __syncthreads();   // all thrU2 reads done before final overwrite
#pragma unroll
    for (int j = 0; j < KNN; ++j) kb[w][lane][j] = kq[j];
    kb[w][lane][KNN] = capped ? 1.0f : 0.0f;
    __syncthreads();

    if (w == 0) {
        bool def = capped;
#pragma unroll
        for (int ow = 1; ow < NLIST; ++ow) {
#pragma unroll
            for (int j = 0; j < KNN; ++j) { float v = kb[ow][lane][j]; INSERT(kq, v); }
            def = def || (kb[ow][lane][KNN] != 0.0f);
        }
        const int orig = (int)g_perm[c][qlist * LISTN + s];
        if (def) {
            unsigned idx = atomicAdd(&g_defer_cnt, 1u);
            g_defer[idx] = ((unsigned)c << 12) | (unsigned)orig;
        } else {
            finish_query(c, kq, orig);
        }
    }
}

// exact cleanup: one wave per deferred query (grid-stride over 8192 waves);
// 64 cands/lane over the 4 lists, butterfly shfl_xor merge of top-10s
__global__ __launch_bounds__(256) void knn_brute(
    const float* __restrict__ pred, const float* __restrict__ gt) {
    const int lane = threadIdx.x & 63;
    const int wid = blockIdx.x * 4 + (threadIdx.x >> 6);
    const unsigned cnt = g_defer_cnt;
    for (unsigned u = wid; u < cnt; u += 8192) {
        const unsigned e = g_defer[u];
        const int c = (int)(e >> 12), orig = (int)(e & 0xFFFu);
        const float* __restrict__ base =
            (c >= BATCH) ? (gt + (c - BATCH) * 3 * NPTS) : (pred + c * 3 * NPTS);
        const float qxv = base[orig], qyv = base[NPTS + orig], qzv = base[2 * NPTS + orig];
        const float a0x = -2.0f * qxv, a0y = -2.0f * qyv, a0z = -2.0f * qzv;

        float kq[KNN];
#pragma unroll
        for (int j = 0; j < KNN; ++j) kq[j] = 1e28f;
#pragma unroll
        for (int L = 0; L < NLIST; ++L) {
#pragma unroll
            for (int r = 0; r < LISTN / 64; ++r) {
                int pos = r * 64 + lane;
                float4 p4 = g_spts[c][L][PAD + pos];
                PROC1(p4, L * LISTN + pos);
            }
        }
#pragma unroll
        for (int off = 32; off >= 1; off >>= 1) {
            float tmp[KNN];
#pragma unroll
            for (int j = 0; j < KNN; ++j) tmp[j] = __shfl_xor(kq[j], off);
#pragma unroll
            for (int j = 0; j < KNN; ++j) INSERT(kq, tmp[j]);
        }
        if (lane == 0) finish_query(c, kq, orig);
    }
}

// loss over 32768 point pairs; one wave-sum atomic per 64 lanes
__global__ __launch_bounds__(256) void cos_loss_kernel(float* __restrict__ out) {
    const int i = blockIdx.x * 256 + threadIdx.x;     // grid sized exactly BN
    float4 p = g_nrm[i];
    float4 g = g_nrm[BN + i];
    float dot = p.x * g.x + p.y * g.y + p.z * g.z;
    float npn = sqrtf(p.x * p.x + p.y * p.y + p.z * p.z);
    float ngn = sqrtf(g.x * g.x + g.y * g.y + g.z * g.z);
    float acc = 1.0f - fabsf(dot / fmaxf(npn * ngn, 1e-8f));
    for (int off = 32; off > 0; off >>= 1) acc += __shfl_down(acc, off);
    if ((threadIdx.x & 63) == 0) atomicAdd(out, acc * (1.0f / (float)BN));
}

extern "C" void kernel_launch(void* const* d_in, const int* in_sizes, int n_in,
                              void* d_out, int out_size, void* d_ws, size_t ws_size,
                              hipStream_t stream) {
    const float* pred = (const float*)d_in[0];
    const float* gt = (const float*)d_in[1];
    float* out = (float*)d_out;

    sort_lists<<<dim3(NCLOUD * NLIST), 512, 0, stream>>>(pred, gt, out);
    knn_walk<<<dim3(64, NCLOUD), 256, 0, stream>>>();
    knn_brute<<<dim3(2048), 256, 0, stream>>>(pred, gt);
    cos_loss_kernel<<<dim3(BN / 256), 256, 0, stream>>>(out);
}